// Round 2
// baseline (1948.881 us; speedup 1.0000x reference)
//
#include <hip/hip_runtime.h>

// ---------------------------------------------------------------------------
// Mamba2-style block on MI355X (gfx950).
// rmsnorm1 -> in_proj GEMM -> causal conv1d -> SSD chunked scan -> z-gate ->
// out_proj GEMM (+residual) -> rmsnorm2 -> gate/up GEMMs -> silu*up ->
// down GEMM (+residual).
// Workspace budget ~194 MiB (bf16 intermediates, single reusable weight buf,
// residual2 lives in d_out).
// ---------------------------------------------------------------------------

typedef unsigned short u16;
typedef __bf16 bf16x8 __attribute__((ext_vector_type(8)));
typedef float f32x4 __attribute__((ext_vector_type(4)));

#define D_MODEL   2048
#define D_INNER   2048
#define NH        32
#define CONV_DIM  6144
#define D_IN_PROJ 8224
#define NPAD      8320      // 65 * 128, padded N for in_proj GEMM tiles
#define DFF       8192
#define BATCH     2
#define SEQ       2048
#define M_TOK     4096
#define NCHUNK    16
#define CHUNK     128

__device__ __forceinline__ u16 f2b(float f) {
  union { float f; unsigned int u; } v; v.f = f;
  unsigned int r = v.u + 0x7FFFu + ((v.u >> 16) & 1u);   // RNE
  return (u16)(r >> 16);
}
__device__ __forceinline__ float b2f(u16 u) {
  union { unsigned int u; float f; } v; v.u = ((unsigned int)u) << 16; return v.f;
}

__device__ __forceinline__ void async16(const void* g, void* l) {
  __builtin_amdgcn_global_load_lds((const __attribute__((address_space(1))) void*)g,
                                   (__attribute__((address_space(3))) void*)l, 16, 0, 0);
}

// ---------------------------------------------------------------------------
// NT bf16 GEMM: C[M,Nreal] = A[M,K] @ W[N,K]^T   (m97-style, 128x128 tile)
// EPI 1: Cf = acc + auxf              (fp32 out; auxf may alias Cf)
// EPI 2: Cb = bf16(acc * silu(auxb))  (bf16 gate values in auxb)
// EPI 3: Cb = bf16(acc), cols >= 8192 also stored fp32 to Fdt (dt slice)
// EPI 4: Cb = bf16(acc)
// ---------------------------------------------------------------------------
template <int EPI>
__global__ void __launch_bounds__(256, 2) gemm_bt(
    const u16* __restrict__ A, const u16* __restrict__ W,
    float* Cf, u16* Cb, const float* auxf, const u16* auxb, float* Fdt,
    int K, int Nreal) {
  __shared__ __align__(16) u16 sA[128 * 32];
  __shared__ __align__(16) u16 sB[128 * 32];
  const int tid = threadIdx.x;
  const int bn = blockIdx.x, bm = blockIdx.y;
  const int lane = tid & 63;
  const int wave = tid >> 6;
  const int wm = (wave >> 1) * 64, wn = (wave & 1) * 64;

  const f32x4 zero4 = {0.f, 0.f, 0.f, 0.f};
  f32x4 acc[4][4];
#pragma unroll
  for (int i = 0; i < 4; ++i)
#pragma unroll
    for (int j = 0; j < 4; ++j) acc[i][j] = zero4;

  const int r0 = tid >> 2;            // 0..63
  const int kk = (tid & 3) * 8;
  const u16* ga0 = A + (size_t)(bm * 128 + r0) * K + kk;
  const u16* ga1 = ga0 + (size_t)64 * K;
  const u16* gb0 = W + (size_t)(bn * 128 + r0) * K + kk;
  const u16* gb1 = gb0 + (size_t)64 * K;
  u16* la0 = &sA[tid * 8]; u16* la1 = &sA[2048 + tid * 8];
  u16* lb0 = &sB[tid * 8]; u16* lb1 = &sB[2048 + tid * 8];

  const int lr = lane & 15;
  const int lk = (lane >> 4) * 8;

  for (int k0 = 0; k0 < K; k0 += 32) {
    async16(ga0, la0); async16(ga1, la1);
    async16(gb0, lb0); async16(gb1, lb1);
    ga0 += 32; ga1 += 32; gb0 += 32; gb1 += 32;
    __syncthreads();
    bf16x8 af[4], bfv[4];
#pragma unroll
    for (int mi = 0; mi < 4; ++mi)
      af[mi] = *(const bf16x8*)&sA[(wm + mi * 16 + lr) * 32 + lk];
#pragma unroll
    for (int ni = 0; ni < 4; ++ni)
      bfv[ni] = *(const bf16x8*)&sB[(wn + ni * 16 + lr) * 32 + lk];
#pragma unroll
    for (int mi = 0; mi < 4; ++mi)
#pragma unroll
      for (int ni = 0; ni < 4; ++ni)
        acc[mi][ni] = __builtin_amdgcn_mfma_f32_16x16x32_bf16(af[mi], bfv[ni], acc[mi][ni], 0, 0, 0);
    __syncthreads();
  }

  const int er = (lane >> 4) * 4;       // C/D: row=(lane>>4)*4+reg, col=lane&15
  const int ec = lane & 15;
#pragma unroll
  for (int mi = 0; mi < 4; ++mi) {
#pragma unroll
    for (int r = 0; r < 4; ++r) {
      const int grow = bm * 128 + wm + mi * 16 + er + r;
#pragma unroll
      for (int ni = 0; ni < 4; ++ni) {
        const int gcol = bn * 128 + wn + ni * 16 + ec;
        if (gcol < Nreal) {
          const size_t idx = (size_t)grow * Nreal + gcol;
          const float v = acc[mi][ni][r];
          if (EPI == 1) {
            Cf[idx] = v + auxf[idx];
          } else if (EPI == 2) {
            const float g = b2f(auxb[idx]);
            const float sg = 1.f / (1.f + __expf(-g));
            Cb[idx] = f2b(v * g * sg);
          } else if (EPI == 3) {
            Cb[idx] = f2b(v);
            if (gcol >= D_INNER + CONV_DIM) Fdt[(size_t)grow * NH + (gcol - (D_INNER + CONV_DIM))] = v;
          } else {
            Cb[idx] = f2b(v);
          }
        }
      }
    }
  }
}

// ---------------------------------------------------------------------------
__global__ void cvt_kernel(const float* __restrict__ s, u16* __restrict__ d, int n4) {
  const int i = blockIdx.x * 256 + threadIdx.x;
  if (i >= n4) return;
  const float4 v = ((const float4*)s)[i];
  ushort4 r;
  r.x = f2b(v.x); r.y = f2b(v.y); r.z = f2b(v.z); r.w = f2b(v.w);
  ((ushort4*)d)[i] = r;
}

__global__ void rmsnorm_kernel(const float* __restrict__ x, const float* __restrict__ w,
                               u16* __restrict__ o) {
  const int row = blockIdx.x;
  const float* xr = x + (size_t)row * D_MODEL;
  float ss = 0.f;
  for (int c = threadIdx.x; c < D_MODEL; c += 256) { const float v = xr[c]; ss += v * v; }
#pragma unroll
  for (int off = 32; off > 0; off >>= 1) ss += __shfl_down(ss, off, 64);
  __shared__ float red[4];
  if ((threadIdx.x & 63) == 0) red[threadIdx.x >> 6] = ss;
  __syncthreads();
  const float scale = rsqrtf((red[0] + red[1] + red[2] + red[3]) * (1.f / D_MODEL) + 1e-5f);
  u16* orow = o + (size_t)row * D_MODEL;
  for (int c = threadIdx.x; c < D_MODEL; c += 256) orow[c] = f2b(xr[c] * scale * w[c]);
}

// causal depthwise conv over seq dim; reads xBC slice of bf16 zxbcdt.
__global__ void conv_kernel(const u16* __restrict__ zx, const float* __restrict__ cw,
                            const float* __restrict__ cb, u16* __restrict__ out) {
  const int idx = blockIdx.x * 256 + threadIdx.x;   // M_TOK * CONV_DIM
  const int ch = idx % CONV_DIM;
  const int m = idx / CONV_DIM;
  const int l = m & (SEQ - 1);
  float accv = cb[ch];
#pragma unroll
  for (int k = 0; k < 4; ++k) {
    const int ls = l - 3 + k;
    if (ls >= 0) accv += cw[ch * 4 + k] * b2f(zx[(size_t)(m - 3 + k) * D_IN_PROJ + D_INNER + ch]);
  }
  out[idx] = f2b(accv);
}

// per (b,chunk,head): cum[i] = sum_{i'<=i} -softplus(dt)   (dt fp32 side buf)
__global__ void dtcum_kernel(const float* __restrict__ dtbuf, float* __restrict__ cum) {
  const int blk = blockIdx.x;                       // b*512 + c*32 + h
  const int h = blk & 31, cc = (blk >> 5) & 15, b = blk >> 9;
  const int i = threadIdx.x;                        // 0..127
  const int m = b * SEQ + cc * CHUNK + i;
  const float dt = dtbuf[(size_t)m * NH + h];
  const float sp = (dt > 20.f) ? dt : log1pf(__expf(dt));
  __shared__ float s[128];
  s[i] = -sp;
  __syncthreads();
  for (int off = 1; off < 128; off <<= 1) {
    const float v = (i >= off) ? s[i - off] : 0.f;
    __syncthreads();
    s[i] += v;
    __syncthreads();
  }
  cum[(size_t)m * NH + h] = s[i];
}

// per (b,chunk,head): S[n][p] = sum_q exp(cum_last - cum_q) * B[q][n] * x[q][p]
__global__ void state_kernel(const u16* __restrict__ xbc, const float* __restrict__ cum,
                             float* __restrict__ S) {
  const int blk = blockIdx.x;
  const int h = blk & 31, cc = (blk >> 5) & 15, b = blk >> 9;
  const int m0 = b * SEQ + cc * CHUNK;
  const int tid = threadIdx.x;
  const int tp = tid & 63, tg = tid >> 6;
  const int n0 = tg * 16;
  const float cl = cum[(size_t)(m0 + 127) * NH + h];
  __shared__ float sBq[32][64], sxq[32][64], sd[32];
  float accv[16];
#pragma unroll
  for (int i = 0; i < 16; ++i) accv[i] = 0.f;
  for (int q0 = 0; q0 < 128; q0 += 32) {
    __syncthreads();
    for (int e = tid; e < 2048; e += 256) {
      const int q = e >> 6, col = e & 63;
      const size_t rowb = (size_t)(m0 + q0 + q) * CONV_DIM;
      sBq[q][col] = b2f(xbc[rowb + D_INNER + h * 64 + col]);
      sxq[q][col] = b2f(xbc[rowb + h * 64 + col]);
    }
    if (tid < 32) sd[tid] = __expf(cl - cum[(size_t)(m0 + q0 + tid) * NH + h]);
    __syncthreads();
    for (int q = 0; q < 32; ++q) {
      const float xv = sxq[q][tp] * sd[q];
#pragma unroll
      for (int i = 0; i < 16; ++i) accv[i] += sBq[q][n0 + i] * xv;
    }
  }
  float* Sp = S + (((size_t)(b * 16 + cc) * NH + h) * 64) * 64;
#pragma unroll
  for (int i = 0; i < 16; ++i) Sp[(size_t)(n0 + i) * 64 + tp] = accv[i];
}

// inter-chunk scan: Hprev[c] = state before chunk c (16 sequential steps)
__global__ void scan_kernel(const float* __restrict__ S, const float* __restrict__ cum,
                            float* __restrict__ H) {
  const int idx = blockIdx.x * 256 + threadIdx.x;   // BATCH*NH*64*64
  const int p = idx & 63, n = (idx >> 6) & 63, h = (idx >> 12) & 31, b = idx >> 17;
  float hs = 0.f;
  for (int cc = 0; cc < NCHUNK; ++cc) {
    const size_t off = (((size_t)(b * 16 + cc) * NH + h) * 64 + n) * 64 + p;
    H[off] = hs;
    const float Ac = __expf(cum[(size_t)(b * SEQ + cc * CHUNK + 127) * NH + h]);
    hs = Ac * hs + S[off];
  }
}

// y = intra + inter + D*x, fused z-silu gate, bf16 out.
// One block per (b, chunk, head, itile of 16 rows).
__global__ void y_kernel(const u16* __restrict__ xbc, const float* __restrict__ cum,
                         const float* __restrict__ H, const float* __restrict__ Dp,
                         const u16* __restrict__ zx, const float* __restrict__ zb,
                         u16* __restrict__ yo) {
  const int blk = blockIdx.x;
  const int it = blk & 7, h = (blk >> 3) & 31, cc = (blk >> 8) & 15, b = blk >> 12;
  const int i0 = it * 16;
  const int m0 = b * SEQ + cc * CHUNK;
  const int tid = threadIdx.x;
  const int tp = tid & 63, tg = tid >> 6;
  __shared__ float sH[64][64];
  __shared__ float sC[16][64];
  __shared__ float sx[16][64];
  __shared__ float sBj[16][64];
  __shared__ float sSc[16][17];
  __shared__ float cum_i[16], cum_j[16];
  const float* Hp = H + (((size_t)(b * 16 + cc) * NH + h) * 64) * 64;
  for (int e = tid; e < 4096; e += 256) sH[e >> 6][e & 63] = Hp[e];
  for (int e = tid; e < 1024; e += 256) {
    const int i = e >> 6, col = e & 63;
    sC[i][col] = b2f(xbc[(size_t)(m0 + i0 + i) * CONV_DIM + 2 * D_INNER + h * 64 + col]);
  }
  if (tid < 16) cum_i[tid] = cum[(size_t)(m0 + i0 + tid) * NH + h];
  __syncthreads();
  float accv[4];
#pragma unroll
  for (int r = 0; r < 4; ++r) {          // y_inter
    const int i = tg * 4 + r;
    float s = 0.f;
    for (int n = 0; n < 64; ++n) s += sC[i][n] * sH[n][tp];
    accv[r] = __expf(cum_i[i]) * s;
  }
  for (int jt = 0; jt <= it; ++jt) {     // y_intra over causal j-tiles
    const int j0 = jt * 16;
    __syncthreads();
    for (int e = tid; e < 1024; e += 256) {
      const int j = e >> 6, col = e & 63;
      const size_t rowb = (size_t)(m0 + j0 + j) * CONV_DIM;
      sBj[j][col] = b2f(xbc[rowb + D_INNER + h * 64 + col]);
      sx[j][col] = b2f(xbc[rowb + h * 64 + col]);
    }
    if (tid < 16) cum_j[tid] = cum[(size_t)(m0 + j0 + tid) * NH + h];
    __syncthreads();
    {
      const int ii = tid >> 4, jj = tid & 15;
      float sc = 0.f;
      if (i0 + ii >= j0 + jj) {
        float d = 0.f;
        for (int n = 0; n < 64; ++n) d += sC[ii][n] * sBj[jj][n];
        sc = __expf(cum_i[ii] - cum_j[jj]) * d;
      }
      sSc[ii][jj] = sc;
    }
    __syncthreads();
#pragma unroll
    for (int r = 0; r < 4; ++r) {
      const int ii = tg * 4 + r;
      for (int jj = 0; jj < 16; ++jj) accv[r] += sSc[ii][jj] * sx[jj][tp];
    }
  }
  const float Dh = Dp[h];
  const int col = h * 64 + tp;
#pragma unroll
  for (int r = 0; r < 4; ++r) {
    const int m = m0 + i0 + tg * 4 + r;
    const float xv = b2f(xbc[(size_t)m * CONV_DIM + col]);
    const float z = b2f(zx[(size_t)m * D_IN_PROJ + col]) + zb[col];
    const float sg = 1.f / (1.f + __expf(-z));
    yo[(size_t)m * D_INNER + col] = f2b((accv[r] + Dh * xv) * z * sg);
  }
}

// ---------------------------------------------------------------------------
extern "C" void kernel_launch(void* const* d_in, const int* in_sizes, int n_in,
                              void* d_out, int out_size, void* d_ws, size_t ws_size,
                              hipStream_t stream) {
  (void)in_sizes; (void)n_in; (void)out_size; (void)ws_size;
  const float* hidden = (const float*)d_in[0];
  const float* w_in   = (const float*)d_in[1];
  const float* z_bias = (const float*)d_in[2];
  const float* conv_w = (const float*)d_in[3];
  const float* conv_b = (const float*)d_in[4];
  const float* Dp     = (const float*)d_in[5];
  const float* w_out  = (const float*)d_in[6];
  const float* n1w    = (const float*)d_in[7];
  const float* n2w    = (const float*)d_in[8];
  const float* w_g    = (const float*)d_in[9];
  const float* w_u    = (const float*)d_in[10];
  const float* w_d    = (const float*)d_in[11];
  float* out = (float*)d_out;

  // ---- workspace layout (~194 MiB total) ----
  char* p = (char*)d_ws;
  auto take = [&](size_t bytes) { char* r = p; p += (bytes + 255) & ~(size_t)255; return r; };
  u16*   Bzx  = (u16*)take((size_t)M_TOK * D_IN_PROJ * 2);              // 64.25 MiB
  u16*   Bxbc = (u16*)take((size_t)M_TOK * CONV_DIM * 2);               // 48 MiB
  float* F_cum = (float*)take((size_t)M_TOK * NH * 4);                  // 0.5 MiB
  float* F_S   = (float*)take((size_t)BATCH * NCHUNK * NH * 64 * 64 * 4); // 16 MiB
  float* F_H   = (float*)take((size_t)BATCH * NCHUNK * NH * 64 * 64 * 4); // 16 MiB
  u16*   B_h   = (u16*)take((size_t)M_TOK * D_MODEL * 2);               // 16 MiB
  float* F_dt  = (float*)take((size_t)M_TOK * NH * 4);                  // 0.5 MiB
  u16*   W_buf = (u16*)take((size_t)NPAD * D_MODEL * 2);                // 32.5 MiB
  // overlays (liveness-checked):
  u16* B_y    = (u16*)F_S;    // y-gated output: F_S dead after scan_kernel
  u16* B_gate = Bzx;          // gate GEMM out: Bzx dead after y_kernel (67.1<=67.4 MiB)
  u16* B_gu   = Bxbc;         // gated-up: spans Bxbc+F_cum+F_S (67.1<=67.6 MiB), all dead
  float* F_res2 = out;        // residual2 lives in d_out

  const int c2 = (D_MODEL * D_INNER / 4 + 255) / 256;
  const int c8 = (DFF * D_MODEL / 4 + 255) / 256;

  // 1. in_proj: convert weight, norm, GEMM (bf16 out + fp32 dt slice)
  cvt_kernel<<<(D_IN_PROJ * D_MODEL / 4 + 255) / 256, 256, 0, stream>>>(w_in, W_buf, D_IN_PROJ * D_MODEL / 4);
  rmsnorm_kernel<<<M_TOK, 256, 0, stream>>>(hidden, n1w, B_h);
  gemm_bt<3><<<dim3(NPAD / 128, M_TOK / 128), 256, 0, stream>>>(B_h, W_buf, nullptr, Bzx, nullptr, nullptr, F_dt, D_MODEL, D_IN_PROJ);

  // 2. conv + SSD scan
  conv_kernel<<<M_TOK * CONV_DIM / 256, 256, 0, stream>>>(Bzx, conv_w, conv_b, Bxbc);
  dtcum_kernel<<<BATCH * NCHUNK * NH, 128, 0, stream>>>(F_dt, F_cum);
  state_kernel<<<BATCH * NCHUNK * NH, 256, 0, stream>>>(Bxbc, F_cum, F_S);
  scan_kernel<<<BATCH * NH * 64 * 64 / 256, 256, 0, stream>>>(F_S, F_cum, F_H);
  y_kernel<<<BATCH * NCHUNK * NH * 8, 256, 0, stream>>>(Bxbc, F_cum, F_H, Dp, Bzx, z_bias, B_y);

  // 3. out_proj (+residual) -> d_out
  cvt_kernel<<<c2, 256, 0, stream>>>(w_out, W_buf, D_MODEL * D_INNER / 4);
  gemm_bt<1><<<dim3(D_MODEL / 128, M_TOK / 128), 256, 0, stream>>>(B_y, W_buf, F_res2, nullptr, hidden, nullptr, nullptr, D_INNER, D_MODEL);

  // 4. MLP: norm2, gate GEMM (bf16), up GEMM (fused silu*gate), down (+residual)
  rmsnorm_kernel<<<M_TOK, 256, 0, stream>>>(F_res2, n2w, B_h);
  cvt_kernel<<<c8, 256, 0, stream>>>(w_g, W_buf, DFF * D_MODEL / 4);
  gemm_bt<4><<<dim3(DFF / 128, M_TOK / 128), 256, 0, stream>>>(B_h, W_buf, nullptr, B_gate, nullptr, nullptr, nullptr, D_MODEL, DFF);
  cvt_kernel<<<c8, 256, 0, stream>>>(w_u, W_buf, DFF * D_MODEL / 4);
  gemm_bt<2><<<dim3(DFF / 128, M_TOK / 128), 256, 0, stream>>>(B_h, W_buf, nullptr, B_gu, nullptr, B_gate, nullptr, D_MODEL, DFF);
  cvt_kernel<<<c8, 256, 0, stream>>>(w_d, W_buf, D_MODEL * DFF / 4);
  gemm_bt<1><<<dim3(D_MODEL / 128, M_TOK / 128), 256, 0, stream>>>(B_gu, W_buf, out, nullptr, F_res2, nullptr, nullptr, DFF, D_MODEL);
}

// Round 3
// 1350.408 us; speedup vs baseline: 1.4432x; 1.4432x over previous
//
#include <hip/hip_runtime.h>

// ---------------------------------------------------------------------------
// Mamba2-style block on MI355X (gfx950).
// rmsnorm1 -> in_proj GEMM -> causal conv1d -> SSD chunked scan -> z-gate ->
// out_proj GEMM (+residual) -> rmsnorm2 -> gate/up GEMMs -> silu*up ->
// down GEMM (+residual).
// R3: y_kernel rewritten as per-(b,chunk,head) MFMA (scores + PV + CH fused).
// ---------------------------------------------------------------------------

typedef unsigned short u16;
typedef __bf16 bf16x8 __attribute__((ext_vector_type(8)));
typedef float f32x4 __attribute__((ext_vector_type(4)));

#define D_MODEL   2048
#define D_INNER   2048
#define NH        32
#define CONV_DIM  6144
#define D_IN_PROJ 8224
#define NPAD      8320      // 65 * 128, padded N for in_proj GEMM tiles
#define DFF       8192
#define BATCH     2
#define SEQ       2048
#define M_TOK     4096
#define NCHUNK    16
#define CHUNK     128

__device__ __forceinline__ u16 f2b(float f) {
  union { float f; unsigned int u; } v; v.f = f;
  unsigned int r = v.u + 0x7FFFu + ((v.u >> 16) & 1u);   // RNE
  return (u16)(r >> 16);
}
__device__ __forceinline__ float b2f(u16 u) {
  union { unsigned int u; float f; } v; v.u = ((unsigned int)u) << 16; return v.f;
}

__device__ __forceinline__ void async16(const void* g, void* l) {
  __builtin_amdgcn_global_load_lds((const __attribute__((address_space(1))) void*)g,
                                   (__attribute__((address_space(3))) void*)l, 16, 0, 0);
}

// ---------------------------------------------------------------------------
// NT bf16 GEMM: C[M,Nreal] = A[M,K] @ W[N,K]^T   (m97-style, 128x128 tile)
// EPI 1: Cf = acc + auxf              (fp32 out; auxf may alias Cf)
// EPI 2: Cb = bf16(acc * silu(auxb))  (bf16 gate values in auxb)
// EPI 3: Cb = bf16(acc), cols >= 8192 also stored fp32 to Fdt (dt slice)
// EPI 4: Cb = bf16(acc)
// ---------------------------------------------------------------------------
template <int EPI>
__global__ void __launch_bounds__(256, 2) gemm_bt(
    const u16* __restrict__ A, const u16* __restrict__ W,
    float* Cf, u16* Cb, const float* auxf, const u16* auxb, float* Fdt,
    int K, int Nreal) {
  __shared__ __align__(16) u16 sA[128 * 32];
  __shared__ __align__(16) u16 sB[128 * 32];
  const int tid = threadIdx.x;
  const int bn = blockIdx.x, bm = blockIdx.y;
  const int lane = tid & 63;
  const int wave = tid >> 6;
  const int wm = (wave >> 1) * 64, wn = (wave & 1) * 64;

  const f32x4 zero4 = {0.f, 0.f, 0.f, 0.f};
  f32x4 acc[4][4];
#pragma unroll
  for (int i = 0; i < 4; ++i)
#pragma unroll
    for (int j = 0; j < 4; ++j) acc[i][j] = zero4;

  const int r0 = tid >> 2;            // 0..63
  const int kk = (tid & 3) * 8;
  const u16* ga0 = A + (size_t)(bm * 128 + r0) * K + kk;
  const u16* ga1 = ga0 + (size_t)64 * K;
  const u16* gb0 = W + (size_t)(bn * 128 + r0) * K + kk;
  const u16* gb1 = gb0 + (size_t)64 * K;
  u16* la0 = &sA[tid * 8]; u16* la1 = &sA[2048 + tid * 8];
  u16* lb0 = &sB[tid * 8]; u16* lb1 = &sB[2048 + tid * 8];

  const int lr = lane & 15;
  const int lk = (lane >> 4) * 8;

  for (int k0 = 0; k0 < K; k0 += 32) {
    async16(ga0, la0); async16(ga1, la1);
    async16(gb0, lb0); async16(gb1, lb1);
    ga0 += 32; ga1 += 32; gb0 += 32; gb1 += 32;
    __syncthreads();
    bf16x8 af[4], bfv[4];
#pragma unroll
    for (int mi = 0; mi < 4; ++mi)
      af[mi] = *(const bf16x8*)&sA[(wm + mi * 16 + lr) * 32 + lk];
#pragma unroll
    for (int ni = 0; ni < 4; ++ni)
      bfv[ni] = *(const bf16x8*)&sB[(wn + ni * 16 + lr) * 32 + lk];
#pragma unroll
    for (int mi = 0; mi < 4; ++mi)
#pragma unroll
      for (int ni = 0; ni < 4; ++ni)
        acc[mi][ni] = __builtin_amdgcn_mfma_f32_16x16x32_bf16(af[mi], bfv[ni], acc[mi][ni], 0, 0, 0);
    __syncthreads();
  }

  const int er = (lane >> 4) * 4;       // C/D: row=(lane>>4)*4+reg, col=lane&15
  const int ec = lane & 15;
#pragma unroll
  for (int mi = 0; mi < 4; ++mi) {
#pragma unroll
    for (int r = 0; r < 4; ++r) {
      const int grow = bm * 128 + wm + mi * 16 + er + r;
#pragma unroll
      for (int ni = 0; ni < 4; ++ni) {
        const int gcol = bn * 128 + wn + ni * 16 + ec;
        if (gcol < Nreal) {
          const size_t idx = (size_t)grow * Nreal + gcol;
          const float v = acc[mi][ni][r];
          if (EPI == 1) {
            Cf[idx] = v + auxf[idx];
          } else if (EPI == 2) {
            const float g = b2f(auxb[idx]);
            const float sg = 1.f / (1.f + __expf(-g));
            Cb[idx] = f2b(v * g * sg);
          } else if (EPI == 3) {
            Cb[idx] = f2b(v);
            if (gcol >= D_INNER + CONV_DIM) Fdt[(size_t)grow * NH + (gcol - (D_INNER + CONV_DIM))] = v;
          } else {
            Cb[idx] = f2b(v);
          }
        }
      }
    }
  }
}

// ---------------------------------------------------------------------------
__global__ void cvt_kernel(const float* __restrict__ s, u16* __restrict__ d, int n4) {
  const int i = blockIdx.x * 256 + threadIdx.x;
  if (i >= n4) return;
  const float4 v = ((const float4*)s)[i];
  ushort4 r;
  r.x = f2b(v.x); r.y = f2b(v.y); r.z = f2b(v.z); r.w = f2b(v.w);
  ((ushort4*)d)[i] = r;
}

__global__ void rmsnorm_kernel(const float* __restrict__ x, const float* __restrict__ w,
                               u16* __restrict__ o) {
  const int row = blockIdx.x;
  const float* xr = x + (size_t)row * D_MODEL;
  float ss = 0.f;
  for (int c = threadIdx.x; c < D_MODEL; c += 256) { const float v = xr[c]; ss += v * v; }
#pragma unroll
  for (int off = 32; off > 0; off >>= 1) ss += __shfl_down(ss, off, 64);
  __shared__ float red[4];
  if ((threadIdx.x & 63) == 0) red[threadIdx.x >> 6] = ss;
  __syncthreads();
  const float scale = rsqrtf((red[0] + red[1] + red[2] + red[3]) * (1.f / D_MODEL) + 1e-5f);
  u16* orow = o + (size_t)row * D_MODEL;
  for (int c = threadIdx.x; c < D_MODEL; c += 256) orow[c] = f2b(xr[c] * scale * w[c]);
}

// causal depthwise conv over seq dim; reads xBC slice of bf16 zxbcdt.
__global__ void conv_kernel(const u16* __restrict__ zx, const float* __restrict__ cw,
                            const float* __restrict__ cb, u16* __restrict__ out) {
  const int idx = blockIdx.x * 256 + threadIdx.x;   // M_TOK * CONV_DIM
  const int ch = idx % CONV_DIM;
  const int m = idx / CONV_DIM;
  const int l = m & (SEQ - 1);
  float accv = cb[ch];
#pragma unroll
  for (int k = 0; k < 4; ++k) {
    const int ls = l - 3 + k;
    if (ls >= 0) accv += cw[ch * 4 + k] * b2f(zx[(size_t)(m - 3 + k) * D_IN_PROJ + D_INNER + ch]);
  }
  out[idx] = f2b(accv);
}

// per (b,chunk,head): cum[i] = sum_{i'<=i} -softplus(dt)   (dt fp32 side buf)
__global__ void dtcum_kernel(const float* __restrict__ dtbuf, float* __restrict__ cum) {
  const int blk = blockIdx.x;                       // b*512 + c*32 + h
  const int h = blk & 31, cc = (blk >> 5) & 15, b = blk >> 9;
  const int i = threadIdx.x;                        // 0..127
  const int m = b * SEQ + cc * CHUNK + i;
  const float dt = dtbuf[(size_t)m * NH + h];
  const float sp = (dt > 20.f) ? dt : log1pf(__expf(dt));
  __shared__ float s[128];
  s[i] = -sp;
  __syncthreads();
  for (int off = 1; off < 128; off <<= 1) {
    const float v = (i >= off) ? s[i - off] : 0.f;
    __syncthreads();
    s[i] += v;
    __syncthreads();
  }
  cum[(size_t)m * NH + h] = s[i];
}

// per (b,chunk,head): S[n][p] = sum_q exp(cum_last - cum_q) * B[q][n] * x[q][p]
__global__ void state_kernel(const u16* __restrict__ xbc, const float* __restrict__ cum,
                             float* __restrict__ S) {
  const int blk = blockIdx.x;
  const int h = blk & 31, cc = (blk >> 5) & 15, b = blk >> 9;
  const int m0 = b * SEQ + cc * CHUNK;
  const int tid = threadIdx.x;
  const int tp = tid & 63, tg = tid >> 6;
  const int n0 = tg * 16;
  const float cl = cum[(size_t)(m0 + 127) * NH + h];
  __shared__ float sBq[32][64], sxq[32][64], sd[32];
  float accv[16];
#pragma unroll
  for (int i = 0; i < 16; ++i) accv[i] = 0.f;
  for (int q0 = 0; q0 < 128; q0 += 32) {
    __syncthreads();
    for (int e = tid; e < 2048; e += 256) {
      const int q = e >> 6, col = e & 63;
      const size_t rowb = (size_t)(m0 + q0 + q) * CONV_DIM;
      sBq[q][col] = b2f(xbc[rowb + D_INNER + h * 64 + col]);
      sxq[q][col] = b2f(xbc[rowb + h * 64 + col]);
    }
    if (tid < 32) sd[tid] = __expf(cl - cum[(size_t)(m0 + q0 + tid) * NH + h]);
    __syncthreads();
    for (int q = 0; q < 32; ++q) {
      const float xv = sxq[q][tp] * sd[q];
#pragma unroll
      for (int i = 0; i < 16; ++i) accv[i] += sBq[q][n0 + i] * xv;
    }
  }
  float* Sp = S + (((size_t)(b * 16 + cc) * NH + h) * 64) * 64;
#pragma unroll
  for (int i = 0; i < 16; ++i) Sp[(size_t)(n0 + i) * 64 + tp] = accv[i];
}

// inter-chunk scan: Hprev[c] = state before chunk c (16 sequential steps)
__global__ void scan_kernel(const float* __restrict__ S, const float* __restrict__ cum,
                            float* __restrict__ H) {
  const int idx = blockIdx.x * 256 + threadIdx.x;   // BATCH*NH*64*64
  const int p = idx & 63, n = (idx >> 6) & 63, h = (idx >> 12) & 31, b = idx >> 17;
  float hs = 0.f;
  for (int cc = 0; cc < NCHUNK; ++cc) {
    const size_t off = (((size_t)(b * 16 + cc) * NH + h) * 64 + n) * 64 + p;
    H[off] = hs;
    const float Ac = __expf(cum[(size_t)(b * SEQ + cc * CHUNK + 127) * NH + h]);
    hs = Ac * hs + S[off];
  }
}

// ---------------------------------------------------------------------------
// y_kernel (MFMA): one block per (b, chunk, head).
// Phase 1: P = mask(exp(cum_i-cum_j) * C·B^T)  [MFMA, bf16 P in LDS]
// Phase 2: Y = P·x + (exp(cum)·C)·H            [MFMA], then +D*x, z-silu gate.
// LDS strides padded (+8 u16) -> 2-way bank aliasing only (free).
// ---------------------------------------------------------------------------
#define SPITCH 136   // sP / sxT row pitch (u16)
#define CPITCH 72    // sC / sB / sHT row pitch (u16)
__global__ void __launch_bounds__(256, 2) y_kernel(
    const u16* __restrict__ xbc, const float* __restrict__ cum,
    const float* __restrict__ H, const float* __restrict__ Dp,
    const u16* __restrict__ zx, const float* __restrict__ zb,
    u16* __restrict__ yo) {
  const int blk = blockIdx.x;            // b*512 + cc*32 + h
  const int h = blk & 31, cc = (blk >> 5) & 15, b = blk >> 9;
  const int m0 = b * SEQ + cc * CHUNK;
  const int tid = threadIdx.x;
  const int lane = tid & 63, wave = tid >> 6;

  __shared__ __align__(16) u16 sC[128 * CPITCH];          // 18 KB  C[i][n] (later exp-scaled)
  __shared__ __align__(16) u16 sU[64 * SPITCH + 64 * CPITCH]; // 26 KB  ph1: sB[j][n]; ph2: sxT[p][j] + sHT[p][n]
  __shared__ __align__(16) u16 sP[128 * SPITCH];          // 34 KB  P[i][j] bf16
  __shared__ float sCum[128];
  u16* sB = sU;
  u16* sxT = sU;
  u16* sHT = sU + 64 * SPITCH;

  // ---- load C, B, cum ----
  {
    const int i = tid >> 4, n4 = (tid & 15) * 4;          // 8 rows/iter, ushort4
    for (int i0 = 0; i0 < 128; i0 += 16) {
      const size_t g = (size_t)(m0 + i0 + i) * CONV_DIM + h * 64 + n4;
      *(ushort4*)&sC[(i0 + i) * CPITCH + n4] = *(const ushort4*)&xbc[g + 2 * D_INNER];
      *(ushort4*)&sB[(i0 + i) * CPITCH + n4] = *(const ushort4*)&xbc[g + D_INNER];
    }
    if (tid < 128) sCum[tid] = cum[(size_t)(m0 + tid) * NH + h];
  }
  __syncthreads();

  const int lr = lane & 15;
  const int lk = (lane >> 4) * 8;
  const int er = (lane >> 4) * 4;
  const int ec = lane & 15;

  // ---- phase 1: scores ----
  {
    const int R = (wave >> 1) * 64, Cq = (wave & 1) * 64;
    const f32x4 z4 = {0.f, 0.f, 0.f, 0.f};
    f32x4 acc[4][4];
#pragma unroll
    for (int i = 0; i < 4; ++i)
#pragma unroll
      for (int j = 0; j < 4; ++j) acc[i][j] = z4;
#pragma unroll
    for (int k0 = 0; k0 < 64; k0 += 32) {
      bf16x8 af[4], bfv[4];
#pragma unroll
      for (int mi = 0; mi < 4; ++mi)
        af[mi] = *(const bf16x8*)&sC[(R + mi * 16 + lr) * CPITCH + k0 + lk];
#pragma unroll
      for (int ni = 0; ni < 4; ++ni)
        bfv[ni] = *(const bf16x8*)&sB[(Cq + ni * 16 + lr) * CPITCH + k0 + lk];
#pragma unroll
      for (int mi = 0; mi < 4; ++mi)
#pragma unroll
        for (int ni = 0; ni < 4; ++ni)
          acc[mi][ni] = __builtin_amdgcn_mfma_f32_16x16x32_bf16(af[mi], bfv[ni], acc[mi][ni], 0, 0, 0);
    }
#pragma unroll
    for (int mi = 0; mi < 4; ++mi)
#pragma unroll
      for (int r = 0; r < 4; ++r) {
        const int row = R + mi * 16 + er + r;
#pragma unroll
        for (int ni = 0; ni < 4; ++ni) {
          const int col = Cq + ni * 16 + ec;
          const float pv = (row >= col) ? __expf(sCum[row] - sCum[col]) * acc[mi][ni][r] : 0.f;
          sP[row * SPITCH + col] = f2b(pv);
        }
      }
  }
  __syncthreads();

  // ---- phase 1.5: scale C rows by exp(cum); load x^T, H^T (overwrite sB) ----
  {
    const int i = tid >> 1, n32 = (tid & 1) * 32;         // sC scale: 128 rows x 64
    const float sc = __expf(sCum[i]);
    for (int n = n32; n < n32 + 32; ++n)
      sC[i * CPITCH + n] = f2b(b2f(sC[i * CPITCH + n]) * sc);
  }
  {
    const int j = tid >> 1, p32 = (tid & 1) * 32;         // x[j][p] -> sxT[p][j]
    const size_t g = (size_t)(m0 + j) * CONV_DIM + h * 64;
    for (int p = p32; p < p32 + 32; ++p)
      sxT[p * SPITCH + j] = xbc[g + p];
    const float* Hp = H + (((size_t)(b * 16 + cc) * NH + h) * 64) * 64;
    if (j < 64) {                                          // H[n][p] -> sHT[p][n]
      const int n = j;
      for (int p = p32; p < p32 + 32; ++p)
        sHT[p * CPITCH + n] = f2b(Hp[n * 64 + p]);
    }
  }
  __syncthreads();

  // ---- phase 2: Y = P·x + Cs·H ----
  {
    const int R2 = wave * 32;
    const f32x4 z4 = {0.f, 0.f, 0.f, 0.f};
    f32x4 acc[2][4];
#pragma unroll
    for (int i = 0; i < 2; ++i)
#pragma unroll
      for (int j = 0; j < 4; ++j) acc[i][j] = z4;
#pragma unroll
    for (int k0 = 0; k0 < 128; k0 += 32) {                 // P·x
      bf16x8 af[2], bfv[4];
#pragma unroll
      for (int mi = 0; mi < 2; ++mi)
        af[mi] = *(const bf16x8*)&sP[(R2 + mi * 16 + lr) * SPITCH + k0 + lk];
#pragma unroll
      for (int ni = 0; ni < 4; ++ni)
        bfv[ni] = *(const bf16x8*)&sxT[(ni * 16 + lr) * SPITCH + k0 + lk];
#pragma unroll
      for (int mi = 0; mi < 2; ++mi)
#pragma unroll
        for (int ni = 0; ni < 4; ++ni)
          acc[mi][ni] = __builtin_amdgcn_mfma_f32_16x16x32_bf16(af[mi], bfv[ni], acc[mi][ni], 0, 0, 0);
    }
#pragma unroll
    for (int k0 = 0; k0 < 64; k0 += 32) {                  // Cs·H
      bf16x8 af[2], bfv[4];
#pragma unroll
      for (int mi = 0; mi < 2; ++mi)
        af[mi] = *(const bf16x8*)&sC[(R2 + mi * 16 + lr) * CPITCH + k0 + lk];
#pragma unroll
      for (int ni = 0; ni < 4; ++ni)
        bfv[ni] = *(const bf16x8*)&sHT[(ni * 16 + lr) * CPITCH + k0 + lk];
#pragma unroll
      for (int mi = 0; mi < 2; ++mi)
#pragma unroll
        for (int ni = 0; ni < 4; ++ni)
          acc[mi][ni] = __builtin_amdgcn_mfma_f32_16x16x32_bf16(af[mi], bfv[ni], acc[mi][ni], 0, 0, 0);
    }
    // epilogue: += D*x, z-silu gate, bf16 store
    const float Dh = Dp[h];
#pragma unroll
    for (int mi = 0; mi < 2; ++mi)
#pragma unroll
      for (int r = 0; r < 4; ++r) {
        const int row = R2 + mi * 16 + er + r;
        const int m = m0 + row;
#pragma unroll
        for (int ni = 0; ni < 4; ++ni) {
          const int p = ni * 16 + ec;
          const int gc = h * 64 + p;
          const float xv = b2f(sxT[p * SPITCH + row]);
          const float z = b2f(zx[(size_t)m * D_IN_PROJ + gc]) + zb[gc];
          const float sg = 1.f / (1.f + __expf(-z));
          yo[(size_t)m * D_INNER + gc] = f2b((acc[mi][ni][r] + Dh * xv) * z * sg);
        }
      }
  }
}

// ---------------------------------------------------------------------------
extern "C" void kernel_launch(void* const* d_in, const int* in_sizes, int n_in,
                              void* d_out, int out_size, void* d_ws, size_t ws_size,
                              hipStream_t stream) {
  (void)in_sizes; (void)n_in; (void)out_size; (void)ws_size;
  const float* hidden = (const float*)d_in[0];
  const float* w_in   = (const float*)d_in[1];
  const float* z_bias = (const float*)d_in[2];
  const float* conv_w = (const float*)d_in[3];
  const float* conv_b = (const float*)d_in[4];
  const float* Dp     = (const float*)d_in[5];
  const float* w_out  = (const float*)d_in[6];
  const float* n1w    = (const float*)d_in[7];
  const float* n2w    = (const float*)d_in[8];
  const float* w_g    = (const float*)d_in[9];
  const float* w_u    = (const float*)d_in[10];
  const float* w_d    = (const float*)d_in[11];
  float* out = (float*)d_out;

  // ---- workspace layout (~194 MiB total) ----
  char* p = (char*)d_ws;
  auto take = [&](size_t bytes) { char* r = p; p += (bytes + 255) & ~(size_t)255; return r; };
  u16*   Bzx  = (u16*)take((size_t)M_TOK * D_IN_PROJ * 2);              // 64.25 MiB
  u16*   Bxbc = (u16*)take((size_t)M_TOK * CONV_DIM * 2);               // 48 MiB
  float* F_cum = (float*)take((size_t)M_TOK * NH * 4);                  // 0.5 MiB
  float* F_S   = (float*)take((size_t)BATCH * NCHUNK * NH * 64 * 64 * 4); // 16 MiB
  float* F_H   = (float*)take((size_t)BATCH * NCHUNK * NH * 64 * 64 * 4); // 16 MiB
  u16*   B_h   = (u16*)take((size_t)M_TOK * D_MODEL * 2);               // 16 MiB
  float* F_dt  = (float*)take((size_t)M_TOK * NH * 4);                  // 0.5 MiB
  u16*   W_buf = (u16*)take((size_t)NPAD * D_MODEL * 2);                // 32.5 MiB
  // overlays (liveness-checked):
  u16* B_y    = (u16*)F_S;    // y-gated output: F_S dead after scan_kernel
  u16* B_gate = Bzx;          // gate GEMM out: Bzx dead after y_kernel
  u16* B_gu   = Bxbc;         // gated-up: spans Bxbc+F_cum+F_S, all dead
  float* F_res2 = out;        // residual2 lives in d_out

  const int c2 = (D_MODEL * D_INNER / 4 + 255) / 256;
  const int c8 = (DFF * D_MODEL / 4 + 255) / 256;

  // 1. in_proj: convert weight, norm, GEMM (bf16 out + fp32 dt slice)
  cvt_kernel<<<(D_IN_PROJ * D_MODEL / 4 + 255) / 256, 256, 0, stream>>>(w_in, W_buf, D_IN_PROJ * D_MODEL / 4);
  rmsnorm_kernel<<<M_TOK, 256, 0, stream>>>(hidden, n1w, B_h);
  gemm_bt<3><<<dim3(NPAD / 128, M_TOK / 128), 256, 0, stream>>>(B_h, W_buf, nullptr, Bzx, nullptr, nullptr, F_dt, D_MODEL, D_IN_PROJ);

  // 2. conv + SSD scan
  conv_kernel<<<M_TOK * CONV_DIM / 256, 256, 0, stream>>>(Bzx, conv_w, conv_b, Bxbc);
  dtcum_kernel<<<BATCH * NCHUNK * NH, 128, 0, stream>>>(F_dt, F_cum);
  state_kernel<<<BATCH * NCHUNK * NH, 256, 0, stream>>>(Bxbc, F_cum, F_S);
  scan_kernel<<<BATCH * NH * 64 * 64 / 256, 256, 0, stream>>>(F_S, F_cum, F_H);
  y_kernel<<<BATCH * NCHUNK * NH, 256, 0, stream>>>(Bxbc, F_cum, F_H, Dp, Bzx, z_bias, B_y);

  // 3. out_proj (+residual) -> d_out
  cvt_kernel<<<c2, 256, 0, stream>>>(w_out, W_buf, D_MODEL * D_INNER / 4);
  gemm_bt<1><<<dim3(D_MODEL / 128, M_TOK / 128), 256, 0, stream>>>(B_y, W_buf, F_res2, nullptr, hidden, nullptr, nullptr, D_INNER, D_MODEL);

  // 4. MLP: norm2, gate GEMM (bf16), up GEMM (fused silu*gate), down (+residual)
  rmsnorm_kernel<<<M_TOK, 256, 0, stream>>>(F_res2, n2w, B_h);
  cvt_kernel<<<c8, 256, 0, stream>>>(w_g, W_buf, DFF * D_MODEL / 4);
  gemm_bt<4><<<dim3(DFF / 128, M_TOK / 128), 256, 0, stream>>>(B_h, W_buf, nullptr, B_gate, nullptr, nullptr, nullptr, D_MODEL, DFF);
  cvt_kernel<<<c8, 256, 0, stream>>>(w_u, W_buf, DFF * D_MODEL / 4);
  gemm_bt<2><<<dim3(DFF / 128, M_TOK / 128), 256, 0, stream>>>(B_h, W_buf, nullptr, B_gu, nullptr, B_gate, nullptr, D_MODEL, DFF);
  cvt_kernel<<<c8, 256, 0, stream>>>(w_d, W_buf, D_MODEL * DFF / 4);
  gemm_bt<1><<<dim3(D_MODEL / 128, M_TOK / 128), 256, 0, stream>>>(B_gu, W_buf, out, nullptr, F_res2, nullptr, nullptr, DFF, D_MODEL);
}

// Round 4
// 1346.395 us; speedup vs baseline: 1.4475x; 1.0030x over previous
//
#include <hip/hip_runtime.h>

// ---------------------------------------------------------------------------
// Mamba2-style block on MI355X (gfx950).
// R4: GEMM occupancy 2->4 blocks/CU (launch_bounds), 128x64 tile variant for
// N=2048 GEMMs (grid-limited at 128x128), GROUP=8 L2 block swizzle.
// ---------------------------------------------------------------------------

typedef unsigned short u16;
typedef __bf16 bf16x8 __attribute__((ext_vector_type(8)));
typedef float f32x4 __attribute__((ext_vector_type(4)));

#define D_MODEL   2048
#define D_INNER   2048
#define NH        32
#define CONV_DIM  6144
#define D_IN_PROJ 8224
#define NPAD      8320      // 65 * 128, padded N for in_proj GEMM tiles
#define DFF       8192
#define BATCH     2
#define SEQ       2048
#define M_TOK     4096
#define NCHUNK    16
#define CHUNK     128

__device__ __forceinline__ u16 f2b(float f) {
  union { float f; unsigned int u; } v; v.f = f;
  unsigned int r = v.u + 0x7FFFu + ((v.u >> 16) & 1u);   // RNE
  return (u16)(r >> 16);
}
__device__ __forceinline__ float b2f(u16 u) {
  union { unsigned int u; float f; } v; v.u = ((unsigned int)u) << 16; return v.f;
}

__device__ __forceinline__ void async16(const void* g, void* l) {
  __builtin_amdgcn_global_load_lds((const __attribute__((address_space(1))) void*)g,
                                   (__attribute__((address_space(3))) void*)l, 16, 0, 0);
}

// ---------------------------------------------------------------------------
// NT bf16 GEMM: C[M,Nreal] = A[M,K] @ W[N,K]^T.  M fixed = 4096 (32 m-tiles).
// TN = 128: 4 waves each 64x64 quadrant.  TN = 64: 4 waves each 32x64 strip.
// 1D grid, GROUP=8 swizzle: 8 consecutive blocks share a W tile.
// EPI 1: Cf = acc + auxf              (fp32 out; auxf may alias Cf)
// EPI 2: Cb = bf16(acc * silu(auxb))  (bf16 gate values in auxb)
// EPI 3: Cb = bf16(acc), cols >= 8192 also stored fp32 to Fdt (dt slice)
// EPI 4: Cb = bf16(acc)
// ---------------------------------------------------------------------------
template <int EPI, int TN>
__global__ void __launch_bounds__(256, 4) gemm_bt(
    const u16* __restrict__ A, const u16* __restrict__ W,
    float* Cf, u16* Cb, const float* auxf, const u16* auxb, float* Fdt,
    int K, int Nreal) {
  constexpr int MI = (TN == 128) ? 4 : 2;
  __shared__ __align__(16) u16 sA[128 * 32];
  __shared__ __align__(16) u16 sB[TN * 32];
  const int tid = threadIdx.x;
  // swizzled tile decode (grid_m = 32)
  const int grid_n = gridDim.x >> 5;
  const int span = grid_n << 3;
  const int pid = blockIdx.x;
  const int bm = ((pid / span) << 3) + ((pid % span) & 7);
  const int bn = (pid % span) >> 3;
  const int lane = tid & 63;
  const int wave = tid >> 6;
  const int wm = (TN == 128) ? (wave >> 1) * 64 : wave * 32;
  const int wn = (TN == 128) ? (wave & 1) * 64 : 0;

  const f32x4 zero4 = {0.f, 0.f, 0.f, 0.f};
  f32x4 acc[MI][4];
#pragma unroll
  for (int i = 0; i < MI; ++i)
#pragma unroll
    for (int j = 0; j < 4; ++j) acc[i][j] = zero4;

  const int r0 = tid >> 2;            // 0..63
  const int kk = (tid & 3) * 8;
  const u16* ga0 = A + (size_t)(bm * 128 + r0) * K + kk;
  const u16* ga1 = ga0 + (size_t)64 * K;
  const u16* gb0 = W + (size_t)(bn * TN + r0) * K + kk;
  const u16* gb1 = gb0 + (size_t)64 * K;          // used only when TN==128
  u16* la0 = &sA[tid * 8]; u16* la1 = &sA[2048 + tid * 8];
  u16* lb0 = &sB[tid * 8]; u16* lb1 = (TN == 128) ? &sB[2048 + tid * 8] : nullptr;

  const int lr = lane & 15;
  const int lk = (lane >> 4) * 8;

  for (int k0 = 0; k0 < K; k0 += 32) {
    async16(ga0, la0); async16(ga1, la1);
    async16(gb0, lb0);
    if (TN == 128) async16(gb1, lb1);
    ga0 += 32; ga1 += 32; gb0 += 32;
    if (TN == 128) gb1 += 32;
    __syncthreads();
    bf16x8 af[MI], bfv[4];
#pragma unroll
    for (int mi = 0; mi < MI; ++mi)
      af[mi] = *(const bf16x8*)&sA[(wm + mi * 16 + lr) * 32 + lk];
#pragma unroll
    for (int ni = 0; ni < 4; ++ni)
      bfv[ni] = *(const bf16x8*)&sB[(wn + ni * 16 + lr) * 32 + lk];
#pragma unroll
    for (int mi = 0; mi < MI; ++mi)
#pragma unroll
      for (int ni = 0; ni < 4; ++ni)
        acc[mi][ni] = __builtin_amdgcn_mfma_f32_16x16x32_bf16(af[mi], bfv[ni], acc[mi][ni], 0, 0, 0);
    __syncthreads();
  }

  const int er = (lane >> 4) * 4;       // C/D: row=(lane>>4)*4+reg, col=lane&15
  const int ec = lane & 15;
#pragma unroll
  for (int mi = 0; mi < MI; ++mi) {
#pragma unroll
    for (int r = 0; r < 4; ++r) {
      const int grow = bm * 128 + wm + mi * 16 + er + r;
#pragma unroll
      for (int ni = 0; ni < 4; ++ni) {
        const int gcol = bn * TN + wn + ni * 16 + ec;
        if (gcol < Nreal) {
          const size_t idx = (size_t)grow * Nreal + gcol;
          const float v = acc[mi][ni][r];
          if (EPI == 1) {
            Cf[idx] = v + auxf[idx];
          } else if (EPI == 2) {
            const float g = b2f(auxb[idx]);
            const float sg = 1.f / (1.f + __expf(-g));
            Cb[idx] = f2b(v * g * sg);
          } else if (EPI == 3) {
            Cb[idx] = f2b(v);
            if (gcol >= D_INNER + CONV_DIM) Fdt[(size_t)grow * NH + (gcol - (D_INNER + CONV_DIM))] = v;
          } else {
            Cb[idx] = f2b(v);
          }
        }
      }
    }
  }
}

// ---------------------------------------------------------------------------
__global__ void cvt_kernel(const float* __restrict__ s, u16* __restrict__ d, int n4) {
  const int i = blockIdx.x * 256 + threadIdx.x;
  if (i >= n4) return;
  const float4 v = ((const float4*)s)[i];
  ushort4 r;
  r.x = f2b(v.x); r.y = f2b(v.y); r.z = f2b(v.z); r.w = f2b(v.w);
  ((ushort4*)d)[i] = r;
}

__global__ void rmsnorm_kernel(const float* __restrict__ x, const float* __restrict__ w,
                               u16* __restrict__ o) {
  const int row = blockIdx.x;
  const float* xr = x + (size_t)row * D_MODEL;
  float ss = 0.f;
  for (int c = threadIdx.x; c < D_MODEL; c += 256) { const float v = xr[c]; ss += v * v; }
#pragma unroll
  for (int off = 32; off > 0; off >>= 1) ss += __shfl_down(ss, off, 64);
  __shared__ float red[4];
  if ((threadIdx.x & 63) == 0) red[threadIdx.x >> 6] = ss;
  __syncthreads();
  const float scale = rsqrtf((red[0] + red[1] + red[2] + red[3]) * (1.f / D_MODEL) + 1e-5f);
  u16* orow = o + (size_t)row * D_MODEL;
  for (int c = threadIdx.x; c < D_MODEL; c += 256) orow[c] = f2b(xr[c] * scale * w[c]);
}

// causal depthwise conv over seq dim; reads xBC slice of bf16 zxbcdt.
__global__ void conv_kernel(const u16* __restrict__ zx, const float* __restrict__ cw,
                            const float* __restrict__ cb, u16* __restrict__ out) {
  const int idx = blockIdx.x * 256 + threadIdx.x;   // M_TOK * CONV_DIM
  const int ch = idx % CONV_DIM;
  const int m = idx / CONV_DIM;
  const int l = m & (SEQ - 1);
  float accv = cb[ch];
#pragma unroll
  for (int k = 0; k < 4; ++k) {
    const int ls = l - 3 + k;
    if (ls >= 0) accv += cw[ch * 4 + k] * b2f(zx[(size_t)(m - 3 + k) * D_IN_PROJ + D_INNER + ch]);
  }
  out[idx] = f2b(accv);
}

// per (b,chunk,head): cum[i] = sum_{i'<=i} -softplus(dt)   (dt fp32 side buf)
__global__ void dtcum_kernel(const float* __restrict__ dtbuf, float* __restrict__ cum) {
  const int blk = blockIdx.x;                       // b*512 + c*32 + h
  const int h = blk & 31, cc = (blk >> 5) & 15, b = blk >> 9;
  const int i = threadIdx.x;                        // 0..127
  const int m = b * SEQ + cc * CHUNK + i;
  const float dt = dtbuf[(size_t)m * NH + h];
  const float sp = (dt > 20.f) ? dt : log1pf(__expf(dt));
  __shared__ float s[128];
  s[i] = -sp;
  __syncthreads();
  for (int off = 1; off < 128; off <<= 1) {
    const float v = (i >= off) ? s[i - off] : 0.f;
    __syncthreads();
    s[i] += v;
    __syncthreads();
  }
  cum[(size_t)m * NH + h] = s[i];
}

// per (b,chunk,head): S[n][p] = sum_q exp(cum_last - cum_q) * B[q][n] * x[q][p]
__global__ void state_kernel(const u16* __restrict__ xbc, const float* __restrict__ cum,
                             float* __restrict__ S) {
  const int blk = blockIdx.x;
  const int h = blk & 31, cc = (blk >> 5) & 15, b = blk >> 9;
  const int m0 = b * SEQ + cc * CHUNK;
  const int tid = threadIdx.x;
  const int tp = tid & 63, tg = tid >> 6;
  const int n0 = tg * 16;
  const float cl = cum[(size_t)(m0 + 127) * NH + h];
  __shared__ float sBq[32][64], sxq[32][64], sd[32];
  float accv[16];
#pragma unroll
  for (int i = 0; i < 16; ++i) accv[i] = 0.f;
  for (int q0 = 0; q0 < 128; q0 += 32) {
    __syncthreads();
    for (int e = tid; e < 2048; e += 256) {
      const int q = e >> 6, col = e & 63;
      const size_t rowb = (size_t)(m0 + q0 + q) * CONV_DIM;
      sBq[q][col] = b2f(xbc[rowb + D_INNER + h * 64 + col]);
      sxq[q][col] = b2f(xbc[rowb + h * 64 + col]);
    }
    if (tid < 32) sd[tid] = __expf(cl - cum[(size_t)(m0 + q0 + tid) * NH + h]);
    __syncthreads();
    for (int q = 0; q < 32; ++q) {
      const float xv = sxq[q][tp] * sd[q];
#pragma unroll
      for (int i = 0; i < 16; ++i) accv[i] += sBq[q][n0 + i] * xv;
    }
  }
  float* Sp = S + (((size_t)(b * 16 + cc) * NH + h) * 64) * 64;
#pragma unroll
  for (int i = 0; i < 16; ++i) Sp[(size_t)(n0 + i) * 64 + tp] = accv[i];
}

// inter-chunk scan: Hprev[c] = state before chunk c (16 sequential steps)
__global__ void scan_kernel(const float* __restrict__ S, const float* __restrict__ cum,
                            float* __restrict__ H) {
  const int idx = blockIdx.x * 256 + threadIdx.x;   // BATCH*NH*64*64
  const int p = idx & 63, n = (idx >> 6) & 63, h = (idx >> 12) & 31, b = idx >> 17;
  float hs = 0.f;
  for (int cc = 0; cc < NCHUNK; ++cc) {
    const size_t off = (((size_t)(b * 16 + cc) * NH + h) * 64 + n) * 64 + p;
    H[off] = hs;
    const float Ac = __expf(cum[(size_t)(b * SEQ + cc * CHUNK + 127) * NH + h]);
    hs = Ac * hs + S[off];
  }
}

// ---------------------------------------------------------------------------
// y_kernel (MFMA): one block per (b, chunk, head).
// Phase 1: P = mask(exp(cum_i-cum_j) * C·B^T)  [MFMA, bf16 P in LDS]
// Phase 2: Y = P·x + (exp(cum)·C)·H            [MFMA], then +D*x, z-silu gate.
// LDS strides padded (+8 u16) -> 2-way bank aliasing only (free).
// ---------------------------------------------------------------------------
#define SPITCH 136   // sP / sxT row pitch (u16)
#define CPITCH 72    // sC / sB / sHT row pitch (u16)
__global__ void __launch_bounds__(256, 2) y_kernel(
    const u16* __restrict__ xbc, const float* __restrict__ cum,
    const float* __restrict__ H, const float* __restrict__ Dp,
    const u16* __restrict__ zx, const float* __restrict__ zb,
    u16* __restrict__ yo) {
  const int blk = blockIdx.x;            // b*512 + cc*32 + h
  const int h = blk & 31, cc = (blk >> 5) & 15, b = blk >> 9;
  const int m0 = b * SEQ + cc * CHUNK;
  const int tid = threadIdx.x;
  const int lane = tid & 63, wave = tid >> 6;

  __shared__ __align__(16) u16 sC[128 * CPITCH];          // 18 KB  C[i][n] (later exp-scaled)
  __shared__ __align__(16) u16 sU[64 * SPITCH + 64 * CPITCH]; // 26 KB  ph1: sB[j][n]; ph2: sxT[p][j] + sHT[p][n]
  __shared__ __align__(16) u16 sP[128 * SPITCH];          // 34 KB  P[i][j] bf16
  __shared__ float sCum[128];
  u16* sB = sU;
  u16* sxT = sU;
  u16* sHT = sU + 64 * SPITCH;

  // ---- load C, B, cum ----
  {
    const int i = tid >> 4, n4 = (tid & 15) * 4;          // 8 rows/iter, ushort4
    for (int i0 = 0; i0 < 128; i0 += 16) {
      const size_t g = (size_t)(m0 + i0 + i) * CONV_DIM + h * 64 + n4;
      *(ushort4*)&sC[(i0 + i) * CPITCH + n4] = *(const ushort4*)&xbc[g + 2 * D_INNER];
      *(ushort4*)&sB[(i0 + i) * CPITCH + n4] = *(const ushort4*)&xbc[g + D_INNER];
    }
    if (tid < 128) sCum[tid] = cum[(size_t)(m0 + tid) * NH + h];
  }
  __syncthreads();

  const int lr = lane & 15;
  const int lk = (lane >> 4) * 8;
  const int er = (lane >> 4) * 4;
  const int ec = lane & 15;

  // ---- phase 1: scores ----
  {
    const int R = (wave >> 1) * 64, Cq = (wave & 1) * 64;
    const f32x4 z4 = {0.f, 0.f, 0.f, 0.f};
    f32x4 acc[4][4];
#pragma unroll
    for (int i = 0; i < 4; ++i)
#pragma unroll
      for (int j = 0; j < 4; ++j) acc[i][j] = z4;
#pragma unroll
    for (int k0 = 0; k0 < 64; k0 += 32) {
      bf16x8 af[4], bfv[4];
#pragma unroll
      for (int mi = 0; mi < 4; ++mi)
        af[mi] = *(const bf16x8*)&sC[(R + mi * 16 + lr) * CPITCH + k0 + lk];
#pragma unroll
      for (int ni = 0; ni < 4; ++ni)
        bfv[ni] = *(const bf16x8*)&sB[(Cq + ni * 16 + lr) * CPITCH + k0 + lk];
#pragma unroll
      for (int mi = 0; mi < 4; ++mi)
#pragma unroll
        for (int ni = 0; ni < 4; ++ni)
          acc[mi][ni] = __builtin_amdgcn_mfma_f32_16x16x32_bf16(af[mi], bfv[ni], acc[mi][ni], 0, 0, 0);
    }
#pragma unroll
    for (int mi = 0; mi < 4; ++mi)
#pragma unroll
      for (int r = 0; r < 4; ++r) {
        const int row = R + mi * 16 + er + r;
#pragma unroll
        for (int ni = 0; ni < 4; ++ni) {
          const int col = Cq + ni * 16 + ec;
          const float pv = (row >= col) ? __expf(sCum[row] - sCum[col]) * acc[mi][ni][r] : 0.f;
          sP[row * SPITCH + col] = f2b(pv);
        }
      }
  }
  __syncthreads();

  // ---- phase 1.5: scale C rows by exp(cum); load x^T, H^T (overwrite sB) ----
  {
    const int i = tid >> 1, n32 = (tid & 1) * 32;         // sC scale: 128 rows x 64
    const float sc = __expf(sCum[i]);
    for (int n = n32; n < n32 + 32; ++n)
      sC[i * CPITCH + n] = f2b(b2f(sC[i * CPITCH + n]) * sc);
  }
  {
    const int j = tid >> 1, p32 = (tid & 1) * 32;         // x[j][p] -> sxT[p][j]
    const size_t g = (size_t)(m0 + j) * CONV_DIM + h * 64;
    for (int p = p32; p < p32 + 32; ++p)
      sxT[p * SPITCH + j] = xbc[g + p];
    const float* Hp = H + (((size_t)(b * 16 + cc) * NH + h) * 64) * 64;
    if (j < 64) {                                          // H[n][p] -> sHT[p][n]
      const int n = j;
      for (int p = p32; p < p32 + 32; ++p)
        sHT[p * CPITCH + n] = f2b(Hp[n * 64 + p]);
    }
  }
  __syncthreads();

  // ---- phase 2: Y = P·x + Cs·H ----
  {
    const int R2 = wave * 32;
    const f32x4 z4 = {0.f, 0.f, 0.f, 0.f};
    f32x4 acc[2][4];
#pragma unroll
    for (int i = 0; i < 2; ++i)
#pragma unroll
      for (int j = 0; j < 4; ++j) acc[i][j] = z4;
#pragma unroll
    for (int k0 = 0; k0 < 128; k0 += 32) {                 // P·x
      bf16x8 af[2], bfv[4];
#pragma unroll
      for (int mi = 0; mi < 2; ++mi)
        af[mi] = *(const bf16x8*)&sP[(R2 + mi * 16 + lr) * SPITCH + k0 + lk];
#pragma unroll
      for (int ni = 0; ni < 4; ++ni)
        bfv[ni] = *(const bf16x8*)&sxT[(ni * 16 + lr) * SPITCH + k0 + lk];
#pragma unroll
      for (int mi = 0; mi < 2; ++mi)
#pragma unroll
        for (int ni = 0; ni < 4; ++ni)
          acc[mi][ni] = __builtin_amdgcn_mfma_f32_16x16x32_bf16(af[mi], bfv[ni], acc[mi][ni], 0, 0, 0);
    }
#pragma unroll
    for (int k0 = 0; k0 < 64; k0 += 32) {                  // Cs·H
      bf16x8 af[2], bfv[4];
#pragma unroll
      for (int mi = 0; mi < 2; ++mi)
        af[mi] = *(const bf16x8*)&sC[(R2 + mi * 16 + lr) * CPITCH + k0 + lk];
#pragma unroll
      for (int ni = 0; ni < 4; ++ni)
        bfv[ni] = *(const bf16x8*)&sHT[(ni * 16 + lr) * CPITCH + k0 + lk];
#pragma unroll
      for (int mi = 0; mi < 2; ++mi)
#pragma unroll
        for (int ni = 0; ni < 4; ++ni)
          acc[mi][ni] = __builtin_amdgcn_mfma_f32_16x16x32_bf16(af[mi], bfv[ni], acc[mi][ni], 0, 0, 0);
    }
    // epilogue: += D*x, z-silu gate, bf16 store
    const float Dh = Dp[h];
#pragma unroll
    for (int mi = 0; mi < 2; ++mi)
#pragma unroll
      for (int r = 0; r < 4; ++r) {
        const int row = R2 + mi * 16 + er + r;
        const int m = m0 + row;
#pragma unroll
        for (int ni = 0; ni < 4; ++ni) {
          const int p = ni * 16 + ec;
          const int gc = h * 64 + p;
          const float xv = b2f(sxT[p * SPITCH + row]);
          const float z = b2f(zx[(size_t)m * D_IN_PROJ + gc]) + zb[gc];
          const float sg = 1.f / (1.f + __expf(-z));
          yo[(size_t)m * D_INNER + gc] = f2b((acc[mi][ni][r] + Dh * xv) * z * sg);
        }
      }
  }
}

// ---------------------------------------------------------------------------
extern "C" void kernel_launch(void* const* d_in, const int* in_sizes, int n_in,
                              void* d_out, int out_size, void* d_ws, size_t ws_size,
                              hipStream_t stream) {
  (void)in_sizes; (void)n_in; (void)out_size; (void)ws_size;
  const float* hidden = (const float*)d_in[0];
  const float* w_in   = (const float*)d_in[1];
  const float* z_bias = (const float*)d_in[2];
  const float* conv_w = (const float*)d_in[3];
  const float* conv_b = (const float*)d_in[4];
  const float* Dp     = (const float*)d_in[5];
  const float* w_out  = (const float*)d_in[6];
  const float* n1w    = (const float*)d_in[7];
  const float* n2w    = (const float*)d_in[8];
  const float* w_g    = (const float*)d_in[9];
  const float* w_u    = (const float*)d_in[10];
  const float* w_d    = (const float*)d_in[11];
  float* out = (float*)d_out;

  // ---- workspace layout (~194 MiB total) ----
  char* p = (char*)d_ws;
  auto take = [&](size_t bytes) { char* r = p; p += (bytes + 255) & ~(size_t)255; return r; };
  u16*   Bzx  = (u16*)take((size_t)M_TOK * D_IN_PROJ * 2);              // 64.25 MiB
  u16*   Bxbc = (u16*)take((size_t)M_TOK * CONV_DIM * 2);               // 48 MiB
  float* F_cum = (float*)take((size_t)M_TOK * NH * 4);                  // 0.5 MiB
  float* F_S   = (float*)take((size_t)BATCH * NCHUNK * NH * 64 * 64 * 4); // 16 MiB
  float* F_H   = (float*)take((size_t)BATCH * NCHUNK * NH * 64 * 64 * 4); // 16 MiB
  u16*   B_h   = (u16*)take((size_t)M_TOK * D_MODEL * 2);               // 16 MiB
  float* F_dt  = (float*)take((size_t)M_TOK * NH * 4);                  // 0.5 MiB
  u16*   W_buf = (u16*)take((size_t)NPAD * D_MODEL * 2);                // 32.5 MiB
  // overlays (liveness-checked):
  u16* B_y    = (u16*)F_S;    // y-gated output: F_S dead after scan_kernel
  u16* B_gate = Bzx;          // gate GEMM out: Bzx dead after y_kernel
  u16* B_gu   = Bxbc;         // gated-up: spans Bxbc+F_cum+F_S, all dead
  float* F_res2 = out;        // residual2 lives in d_out

  const int c2 = (D_MODEL * D_INNER / 4 + 255) / 256;
  const int c8 = (DFF * D_MODEL / 4 + 255) / 256;

  // 1. in_proj: convert weight, norm, GEMM (bf16 out + fp32 dt slice)
  cvt_kernel<<<(D_IN_PROJ * D_MODEL / 4 + 255) / 256, 256, 0, stream>>>(w_in, W_buf, D_IN_PROJ * D_MODEL / 4);
  rmsnorm_kernel<<<M_TOK, 256, 0, stream>>>(hidden, n1w, B_h);
  gemm_bt<3, 128><<<(NPAD / 128) * 32, 256, 0, stream>>>(B_h, W_buf, nullptr, Bzx, nullptr, nullptr, F_dt, D_MODEL, D_IN_PROJ);

  // 2. conv + SSD scan
  conv_kernel<<<M_TOK * CONV_DIM / 256, 256, 0, stream>>>(Bzx, conv_w, conv_b, Bxbc);
  dtcum_kernel<<<BATCH * NCHUNK * NH, 128, 0, stream>>>(F_dt, F_cum);
  state_kernel<<<BATCH * NCHUNK * NH, 256, 0, stream>>>(Bxbc, F_cum, F_S);
  scan_kernel<<<BATCH * NH * 64 * 64 / 256, 256, 0, stream>>>(F_S, F_cum, F_H);
  y_kernel<<<BATCH * NCHUNK * NH, 256, 0, stream>>>(Bxbc, F_cum, F_H, Dp, Bzx, z_bias, B_y);

  // 3. out_proj (+residual) -> d_out   (TN=64: 1024 blocks)
  cvt_kernel<<<c2, 256, 0, stream>>>(w_out, W_buf, D_MODEL * D_INNER / 4);
  gemm_bt<1, 64><<<(D_MODEL / 64) * 32, 256, 0, stream>>>(B_y, W_buf, F_res2, nullptr, hidden, nullptr, nullptr, D_INNER, D_MODEL);

  // 4. MLP: norm2, gate GEMM (bf16), up GEMM (fused silu*gate), down (+residual)
  rmsnorm_kernel<<<M_TOK, 256, 0, stream>>>(F_res2, n2w, B_h);
  cvt_kernel<<<c8, 256, 0, stream>>>(w_g, W_buf, DFF * D_MODEL / 4);
  gemm_bt<4, 128><<<(DFF / 128) * 32, 256, 0, stream>>>(B_h, W_buf, nullptr, B_gate, nullptr, nullptr, nullptr, D_MODEL, DFF);
  cvt_kernel<<<c8, 256, 0, stream>>>(w_u, W_buf, DFF * D_MODEL / 4);
  gemm_bt<2, 128><<<(DFF / 128) * 32, 256, 0, stream>>>(B_h, W_buf, nullptr, B_gu, nullptr, B_gate, nullptr, D_MODEL, DFF);
  cvt_kernel<<<c8, 256, 0, stream>>>(w_d, W_buf, D_MODEL * DFF / 4);
  gemm_bt<1, 64><<<(D_MODEL / 64) * 32, 256, 0, stream>>>(B_gu, W_buf, out, nullptr, F_res2, nullptr, nullptr, DFF, D_MODEL);
}